// Round 4
// baseline (1107.957 us; speedup 1.0000x reference)
//
#include <hip/hip_runtime.h>

#define BB 8
#define TT 16
#define CIN 32
#define HID 64
#define HH 64
#define WW 64
#define EPS 1e-3f
#define NEG_SLOPE 0.01f

typedef short s16x8 __attribute__((ext_vector_type(8)));
typedef _Float16 hx8 __attribute__((ext_vector_type(8)));
typedef float fx4 __attribute__((ext_vector_type(4)));

static __device__ __forceinline__ hx8 as_h(s16x8 v) {
    union { s16x8 s; hx8 h; } u; u.s = v; return u.h;
}
__device__ __forceinline__ float tanh_fast(float x) {
    x = fminf(fmaxf(x, -15.f), 15.f);
    float e = __expf(-2.f * x);
    return (1.f - e) / (1.f + e);
}

// x (NCHW fp32) -> xcl [b][t][y*64+x][32] f16
__global__ __launch_bounds__(256) void x2h(const float* __restrict__ x,
                                           _Float16* __restrict__ xcl) {
    __shared__ float s[32][65];
    int y = blockIdx.x, t = blockIdx.y, b = blockIdx.z;
    int tid = threadIdx.x;
    const float* src = x + (((size_t)(b * TT + t) * CIN) * HH + y) * WW;
#pragma unroll
    for (int k = 0; k < 8; ++k) {
        int idx = tid + k * 256;
        int c = idx >> 6, xx = idx & 63;
        s[c][xx] = src[(size_t)c * HH * WW + xx];
    }
    __syncthreads();
    int xx = tid >> 2, c0 = (tid & 3) * 8;
    _Float16 tmp[8];
#pragma unroll
    for (int j = 0; j < 8; ++j) tmp[j] = (_Float16)s[c0 + j][xx];
    _Float16* dst = xcl + (((size_t)(b * TT + t) * 4096) + y * 64 + xx) * 32 + c0;
    *(hx8*)dst = *(hx8*)tmp;
}

// w [256 oc][96 ch][3][3] fp32 -> wpk [tap(9)][kc(3)][kq(4)][n(256)][k7(8)] f16
// n-mapping: gate=(n>>4)&3, hid=(n>>6)*16+(n&15), oc=gate*64+hid
// channel ks = kc*32 + kq*8 + k7 of concat [x(32), h(64)]
__global__ __launch_bounds__(256) void pack_wh(const float* __restrict__ w,
                                               _Float16* __restrict__ wpk) {
    int idx = blockIdx.x * 256 + threadIdx.x;
    if (idx >= 256 * 864) return;
    int k7 = idx & 7;
    int j = idx >> 3;
    int n = j & 255;
    int kk = j >> 8;            // tap*12 + kc*4 + kq
    int tap = kk / 12;
    int r12 = kk % 12;
    int ks = (r12 >> 2) * 32 + (r12 & 3) * 8 + k7;
    int gate = (n >> 4) & 3;
    int hid  = (n >> 6) * 16 + (n & 15);
    int oc   = gate * 64 + hid;
    wpk[idx] = (_Float16)w[((size_t)oc * 96 + ks) * 9 + tap];
}

// Persistent ConvLSTM, 16 steps, per-row flag pipeline (no cooperative launch).
// grid 256 (r 0..31 x b 0..7) x 512 thr = 8 waves. Occupancy floor is
// 1 block/CU and grid == 256 == #CUs, so all blocks are co-resident by
// construction -> the neighbor-flag spin cannot deadlock. Block owns rows
// 2r,2r+1 for all t; c-state and stats live in registers.
// h ping-pongs between two buffers; write-safety: flags[r+-1] >= t observed
// before writing h(t) over h(t-2) implies neighbors finished reading h(t-2).
// Coherence: writer releases (wbl2) before flag store; reader acquires
// (buffer_inv) after flag wait, so stale h(t-3) lines cannot be read.
__global__ __launch_bounds__(512, 2) void lstm_persist(
    const _Float16* __restrict__ xcl,
    const _Float16* __restrict__ wpk,
    const float* __restrict__ bias,
    _Float16* __restrict__ hA,
    _Float16* __restrict__ hB,
    float* __restrict__ out,
    float* __restrict__ partial,
    int* __restrict__ flags) {
    const int bid = blockIdx.x;
    const int r = bid & 31, b = bid >> 5;
    const int tid = threadIdx.x;
    const int lane15 = tid & 15;
    const int kq = (tid >> 4) & 3;
    const int w = tid >> 6;          // 0..7
    const int w4 = w & 3;            // N quadrant
    const int rs = w >> 2;           // row select
    const int yy = 2 * r + rs;       // my output row

    __shared__ __align__(16) unsigned short s_h[4 * 66 * 72];   // 38,016 B

    const int hid = w4 * 16 + lane15;
    const float bi = bias[hid], bff = bias[64 + hid];
    const float bo = bias[128 + hid], bg = bias[192 + hid];

    fx4 cst[4];
#pragma unroll
    for (int m = 0; m < 4; ++m) cst[m] = (fx4)0.f;
    float osum = 0.f, osum2 = 0.f;

#pragma unroll 1
    for (int t = 0; t < TT; ++t) {
        fx4 acc[4][4];
#pragma unroll
        for (int m = 0; m < 4; ++m)
#pragma unroll
            for (int g = 0; g < 4; ++g) acc[m][g] = (fx4)0.f;

        // ---- X taps: A-frags direct from L2-resident xcl (no flag dependency) ----
        const short* xb_t = (const short*)xcl + (size_t)(b * TT + t) * 4096 * 32;
#pragma unroll
        for (int tap = 0; tap < 9; ++tap) {
            const int ky = tap / 3, kx = tap % 3;
            const int iy = yy + ky - 1;            // wave-uniform
            hx8 bf[4];
#pragma unroll
            for (int g = 0; g < 4; ++g) {
                int n = (4 * w4 + g) * 16 + lane15;
                bf[g] = *(const hx8*)(wpk + ((size_t)((tap * 12 + kq) * 256 + n)) * 8);
            }
            if (iy >= 0 && iy < 64) {
                hx8 af[4];
#pragma unroll
                for (int m = 0; m < 4; ++m) {
                    int ix = m * 16 + lane15 + kx - 1;
                    s16x8 v = (s16x8)0;
                    if (ix >= 0 && ix < 64)
                        v = *(const s16x8*)(xb_t + ((size_t)iy * 64 + ix) * 32 + kq * 8);
                    af[m] = as_h(v);
                }
#pragma unroll
                for (int m = 0; m < 4; ++m)
#pragma unroll
                    for (int g = 0; g < 4; ++g)
                        acc[m][g] = __builtin_amdgcn_mfma_f32_16x16x32_f16(af[m], bf[g], acc[m][g], 0, 0, 0);
            }
        }

        // ---- H contribution (t>0) ----
        if (t > 0) {
            // wait for neighbor rows' h(t-1); 2 lanes spin in parallel.
            // Bounded spin (~0.5 s) as a failsafe: converts a would-be hang
            // into a wrong-answer diagnostic instead of a dead container.
            if (tid < 2) {
                int nb = r + (tid ? 1 : -1);
                if (nb >= 0 && nb < 32) {
                    const int fid = b * 32 + nb;
                    int spins = 0;
                    while (__hip_atomic_load(&flags[fid], __ATOMIC_RELAXED,
                                             __HIP_MEMORY_SCOPE_AGENT) < t) {
                        __builtin_amdgcn_s_sleep(4);
                        if (++spins > (1 << 22)) break;
                    }
                }
            }
            __syncthreads();
            // acquire: invalidate stale L1/L2 copies of the h buffer we are
            // about to read (it was last touched 2 steps ago).
            __builtin_amdgcn_fence(__ATOMIC_ACQUIRE, "agent");

            const short* hin = (const short*)((t & 1) ? hA : hB);
            // stage 4 rows x 66 cols x 64ch f16 @ stride 72 shorts: 2112 b128 units
#pragma unroll
            for (int k2 = 0; k2 < 4; ++k2) {
                int u = tid + k2 * 512;
                int unit = u & 7, pix = u >> 3;
                int col = pix % 66, lr = pix / 66;
                int iy = 2 * r + lr - 1, ix = col - 1;
                s16x8 v = (s16x8)0;
                if (iy >= 0 && iy < 64 && ix >= 0 && ix < 64)
                    v = *(const s16x8*)(hin + ((size_t)b * 4096 + iy * 64 + ix) * 64 + unit * 8);
                *(s16x8*)(s_h + (lr * 66 + col) * 72 + unit * 8) = v;
            }
            if (tid < 64) {
                int u = 2048 + tid;
                int unit = u & 7, pix = u >> 3;
                int col = pix % 66, lr = pix / 66;
                int iy = 2 * r + lr - 1, ix = col - 1;
                s16x8 v = (s16x8)0;
                if (iy >= 0 && iy < 64 && ix >= 0 && ix < 64)
                    v = *(const s16x8*)(hin + ((size_t)b * 4096 + iy * 64 + ix) * 64 + unit * 8);
                *(s16x8*)(s_h + (lr * 66 + col) * 72 + unit * 8) = v;
            }
            __syncthreads();

#pragma unroll
            for (int tap = 0; tap < 9; ++tap) {
                const int ky = tap / 3, kx = tap % 3;
#pragma unroll
                for (int hc = 0; hc < 2; ++hc) {
                    hx8 bf[4];
#pragma unroll
                    for (int g = 0; g < 4; ++g) {
                        int n = (4 * w4 + g) * 16 + lane15;
                        bf[g] = *(const hx8*)(wpk + ((size_t)((tap * 12 + (hc + 1) * 4 + kq) * 256 + n)) * 8);
                    }
                    hx8 af[4];
#pragma unroll
                    for (int m = 0; m < 4; ++m) {
                        int col = m * 16 + lane15 + kx;
                        af[m] = *(const hx8*)(s_h + ((rs + ky) * 66 + col) * 72 + hc * 32 + kq * 8);
                    }
#pragma unroll
                    for (int m = 0; m < 4; ++m)
#pragma unroll
                        for (int g = 0; g < 4; ++g)
                            acc[m][g] = __builtin_amdgcn_mfma_f32_16x16x32_f16(af[m], bf[g], acc[m][g], 0, 0, 0);
                }
            }
        }

        // ---- Epilogue: gate math; c-state in registers ----
        _Float16* hout = (t & 1) ? hB : hA;
#pragma unroll
        for (int m = 0; m < 4; ++m) {
            int xb = m * 16 + kq * 4;
            size_t pixbase = (size_t)b * 4096 + (size_t)yy * 64 + xb;
            float4 o4;
#pragma unroll
            for (int r4 = 0; r4 < 4; ++r4) {
                float ci = acc[m][0][r4] + bi;
                float cf = acc[m][1][r4] + bff;
                float co = acc[m][2][r4] + bo;
                float cg_ = acc[m][3][r4] + bg;
                float c_old = cst[m][r4];
                float si = 1.f / (1.f + __expf(-ci));
                float sf = 1.f / (1.f + __expf(-cf));
                float so = 1.f / (1.f + __expf(-co));
                float c_new = sf * c_old + si * tanh_fast(cg_);
                float h = so * tanh_fast(c_new);
                cst[m][r4] = c_new;
                if (t < TT - 1)
                    hout[(pixbase + r4) * 64 + hid] = (_Float16)h;
                float ov = (h >= 0.f) ? h : NEG_SLOPE * h;
                (&o4.x)[r4] = ov;
                osum += ov;
                osum2 += ov * ov;
            }
            *(float4*)(out + (((size_t)(b * TT + t) * 64 + hid) * 64 + yy) * 64 + xb) = o4;
        }

        // ---- Publish h(t): drain stores, release-flush L2, bump flag ----
        if (t < TT - 1) {
            __syncthreads();   // each wave drains vmcnt before s_barrier
            if (tid == 0) {
                __builtin_amdgcn_fence(__ATOMIC_RELEASE, "agent");   // buffer_wbl2
                __hip_atomic_store(&flags[b * 32 + r], t + 1,
                                   __ATOMIC_RELEASE, __HIP_MEMORY_SCOPE_AGENT);
            }
        }
    }

    osum  += __shfl_xor(osum, 16);  osum  += __shfl_xor(osum, 32);
    osum2 += __shfl_xor(osum2, 16); osum2 += __shfl_xor(osum2, 32);
    if (kq == 0) {
        int row = b * 64 + yy;
        partial[row * 128 + hid] = osum;
        partial[row * 128 + 64 + hid] = osum2;
    }
}

__global__ __launch_bounds__(512) void finalize_stats(const float* __restrict__ partial,
                                                      float* __restrict__ stats,
                                                      const float* __restrict__ gamma,
                                                      const float* __restrict__ beta) {
    int idx = threadIdx.x & 127;
    int seg = threadIdx.x >> 7;       // 0..3, each sums 128 of 512 rows
    float s = 0.f;
    for (int k = seg * 128; k < seg * 128 + 128; ++k) s += partial[k * 128 + idx];
    __shared__ float red[4][128];
    red[seg][idx] = s;
    __syncthreads();
    if (threadIdx.x < 64) {
        int hid = threadIdx.x;
        const float n = (float)((size_t)BB * TT * HH * WW);
        float mean = (red[0][hid] + red[1][hid] + red[2][hid] + red[3][hid]) / n;
        float var  = (red[0][64 + hid] + red[1][64 + hid] + red[2][64 + hid] + red[3][64 + hid]) / n
                     - mean * mean;
        float inv  = rsqrtf(var + EPS);
        float sc   = gamma[hid] * inv;
        stats[hid]      = sc;
        stats[64 + hid] = beta[hid] - mean * sc;
    }
}

__global__ __launch_bounds__(256) void normalize_k(float* __restrict__ out,
                                                   const float* __restrict__ stats) {
    const size_t N = (size_t)BB * TT * HID * HH * WW;
    size_t i = ((size_t)blockIdx.x * blockDim.x + threadIdx.x) * 4;
    size_t stride = (size_t)gridDim.x * blockDim.x * 4;
    for (; i < N; i += stride) {
        int ch = (int)((i >> 12) & (HID - 1));
        float sc = stats[ch], sh = stats[64 + ch];
        float4 v = *(float4*)(out + i);
        v.x = fmaf(v.x, sc, sh);
        v.y = fmaf(v.y, sc, sh);
        v.z = fmaf(v.z, sc, sh);
        v.w = fmaf(v.w, sc, sh);
        *(float4*)(out + i) = v;
    }
}

extern "C" void kernel_launch(void* const* d_in, const int* in_sizes, int n_in,
                              void* d_out, int out_size, void* d_ws, size_t ws_size,
                              hipStream_t stream) {
    const float* x     = (const float*)d_in[0];
    const float* w     = (const float*)d_in[1];
    const float* bias  = (const float*)d_in[2];
    const float* gamma = (const float*)d_in[3];
    const float* beta  = (const float*)d_in[4];
    float* out = (float*)d_out;
    char* wsb = (char*)d_ws;

    // Total workspace use: 42,649,088 B (within the 59.3 MB proven bound;
    // round 3's 101 MB layout is the suspected container killer).
    _Float16* xcl   = (_Float16*)(wsb);                    // 33,554,432 B
    _Float16* wpk   = (_Float16*)(wsb + 33554432);         //    442,368 B
    _Float16* hA    = (_Float16*)(wsb + 33996800);         //  4,194,304 B
    _Float16* hB    = (_Float16*)(wsb + 38191104);         //  4,194,304 B
    float* partial  = (float*)(wsb + 42385408);            //    262,144 B
    float* stats    = (float*)(wsb + 42647552);            //        512 B
    int*   flags    = (int*)(wsb + 42648064);              //      1,024 B

    hipMemsetAsync(flags, 0, 1024, stream);

    x2h<<<dim3(64, 16, 8), 256, 0, stream>>>(x, xcl);
    pack_wh<<<864, 256, 0, stream>>>(w, wpk);

    lstm_persist<<<256, 512, 0, stream>>>(xcl, wpk, bias, hA, hB, out, partial, flags);

    finalize_stats<<<1, 512, 0, stream>>>(partial, stats, gamma, beta);
    normalize_k<<<8192, 256, 0, stream>>>(out, stats);
}

// Round 5
// 651.094 us; speedup vs baseline: 1.7017x; 1.7017x over previous
//
#include <hip/hip_runtime.h>

#define BB 8
#define TT 16
#define CIN 32
#define HID 64
#define HH 64
#define WW 64
#define EPS 1e-3f
#define NEG_SLOPE 0.01f

typedef short s16x8 __attribute__((ext_vector_type(8)));
typedef _Float16 hx8 __attribute__((ext_vector_type(8)));
typedef float fx4 __attribute__((ext_vector_type(4)));

static __device__ __forceinline__ hx8 as_h(s16x8 v) {
    union { s16x8 s; hx8 h; } u; u.s = v; return u.h;
}
__device__ __forceinline__ float tanh_fast(float x) {
    x = fminf(fmaxf(x, -15.f), 15.f);
    float e = __expf(-2.f * x);
    return (1.f - e) / (1.f + e);
}

// x (NCHW fp32) -> xcl [b][t][y*64+x][32] f16
__global__ __launch_bounds__(256) void x2h(const float* __restrict__ x,
                                           _Float16* __restrict__ xcl) {
    __shared__ float s[32][65];
    int y = blockIdx.x, t = blockIdx.y, b = blockIdx.z;
    int tid = threadIdx.x;
    const float* src = x + (((size_t)(b * TT + t) * CIN) * HH + y) * WW;
#pragma unroll
    for (int k = 0; k < 8; ++k) {
        int idx = tid + k * 256;
        int c = idx >> 6, xx = idx & 63;
        s[c][xx] = src[(size_t)c * HH * WW + xx];
    }
    __syncthreads();
    int xx = tid >> 2, c0 = (tid & 3) * 8;
    _Float16 tmp[8];
#pragma unroll
    for (int j = 0; j < 8; ++j) tmp[j] = (_Float16)s[c0 + j][xx];
    _Float16* dst = xcl + (((size_t)(b * TT + t) * 4096) + y * 64 + xx) * 32 + c0;
    *(hx8*)dst = *(hx8*)tmp;
}

// w [256 oc][96 ch][3][3] fp32 -> wpk [tap(9)][kc(3)][kq(4)][n(256)][k7(8)] f16
// n-mapping: gate=(n>>4)&3, hid=(n>>6)*16+(n&15), oc=gate*64+hid
// channel ks = kc*32 + kq*8 + k7 of concat [x(32), h(64)]
__global__ __launch_bounds__(256) void pack_wh(const float* __restrict__ w,
                                               _Float16* __restrict__ wpk) {
    int idx = blockIdx.x * 256 + threadIdx.x;
    if (idx >= 256 * 864) return;
    int k7 = idx & 7;
    int j = idx >> 3;
    int n = j & 255;
    int kk = j >> 8;            // tap*12 + kc*4 + kq
    int tap = kk / 12;
    int r12 = kk % 12;
    int ks = (r12 >> 2) * 32 + (r12 & 3) * 8 + k7;
    int gate = (n >> 4) & 3;
    int hid  = (n >> 6) * 16 + (n & 15);
    int oc   = gate * 64 + hid;
    wpk[idx] = (_Float16)w[((size_t)oc * 96 + ks) * 9 + tap];
}

// One timestep. grid (64 rows, 8 b) x 512 thr = 8 waves.
// __launch_bounds__(512,4): VGPR<=128 -> 2 blocks/CU = 16 waves/CU = 4/SIMD
// (every prior round ran at 2/SIMD; all pipes were ~80% idle -> latency-bound).
// Wave w: w4 = w&3 is N-quadrant (64 hid x gate), mh = w>>2 is M-half
// (x in [mh*32, mh*32+32)). mh twins read identical weights -> L1 dedup.
// M=64 (one row), N=256 (4 gates x 64 hid), K=96/tap x 9 taps, all f16.
__global__ __launch_bounds__(512, 4) void lstm_step(
    const _Float16* __restrict__ xcl,
    const _Float16* __restrict__ wpk,
    const float* __restrict__ bias,
    const _Float16* __restrict__ h_in,
    _Float16* __restrict__ h_out,
    float* __restrict__ c_ws,
    float* __restrict__ out,
    float* __restrict__ partial,
    int t) {
    const int y0 = blockIdx.x, b = blockIdx.y;
    const int tid = threadIdx.x;
    const int lane15 = tid & 15;
    const int kq = (tid >> 4) & 3;
    const int w = tid >> 6;          // 0..7
    const int w4 = w & 3;            // N quadrant
    const int mh = w >> 2;           // M half

    __shared__ __align__(16) unsigned short s_h[3 * 66 * 72];   // 28,512 B

    fx4 acc[2][4];
#pragma unroll
    for (int m = 0; m < 2; ++m)
#pragma unroll
        for (int g = 0; g < 4; ++g) acc[m][g] = (fx4)0.f;

    // ---- stage h tile (t>0): 3 rows x 66 x 64ch f16 @ stride 72 shorts ----
    if (t > 0) {
        for (int u = tid; u < 3 * 66 * 8; u += 512) {
            int unit = u & 7, pix = u >> 3;
            int col = pix % 66, r = pix / 66;
            int iy = y0 + r - 1, ix = col - 1;
            s16x8 v = (s16x8)0;
            if (iy >= 0 && iy < 64 && ix >= 0 && ix < 64)
                v = *(const s16x8*)((const short*)h_in +
                                    ((size_t)(b * 64 + iy) * 64 + ix) * 64 + unit * 8);
            *(s16x8*)(s_h + (r * 66 + col) * 72 + unit * 8) = v;
        }
    }

    // ---- X taps: A-frags direct from L2-resident xcl (no LDS dependency) ----
    const short* xb_t = (const short*)xcl + (size_t)(b * TT + t) * 4096 * 32;
#pragma unroll
    for (int tap = 0; tap < 9; ++tap) {
        const int ky = tap / 3, kx = tap % 3;
        const int iy = y0 + ky - 1;            // block-uniform
        hx8 bf[4];
#pragma unroll
        for (int g = 0; g < 4; ++g) {
            int n = (4 * w4 + g) * 16 + lane15;
            bf[g] = *(const hx8*)(wpk + ((size_t)((tap * 12 + kq) * 256 + n)) * 8);
        }
        if (iy >= 0 && iy < 64) {
            hx8 af[2];
#pragma unroll
            for (int m = 0; m < 2; ++m) {
                int ix = (mh * 2 + m) * 16 + lane15 + kx - 1;
                s16x8 v = (s16x8)0;
                if (ix >= 0 && ix < 64)
                    v = *(const s16x8*)(xb_t + ((size_t)iy * 64 + ix) * 32 + kq * 8);
                af[m] = as_h(v);
            }
#pragma unroll
            for (int m = 0; m < 2; ++m)
#pragma unroll
                for (int g = 0; g < 4; ++g)
                    acc[m][g] = __builtin_amdgcn_mfma_f32_16x16x32_f16(af[m], bf[g], acc[m][g], 0, 0, 0);
        }
    }

    // ---- H taps from LDS (t>0) ----
    if (t > 0) {
        __syncthreads();
#pragma unroll
        for (int tap = 0; tap < 9; ++tap) {
            const int ky = tap / 3, kx = tap % 3;
#pragma unroll
            for (int hc = 0; hc < 2; ++hc) {
                hx8 bf[4];
#pragma unroll
                for (int g = 0; g < 4; ++g) {
                    int n = (4 * w4 + g) * 16 + lane15;
                    bf[g] = *(const hx8*)(wpk + ((size_t)((tap * 12 + (hc + 1) * 4 + kq) * 256 + n)) * 8);
                }
                hx8 af[2];
#pragma unroll
                for (int m = 0; m < 2; ++m) {
                    int col = (mh * 2 + m) * 16 + lane15 + kx;
                    af[m] = *(const hx8*)(s_h + (ky * 66 + col) * 72 + hc * 32 + kq * 8);
                }
#pragma unroll
                for (int m = 0; m < 2; ++m)
#pragma unroll
                    for (int g = 0; g < 4; ++g)
                        acc[m][g] = __builtin_amdgcn_mfma_f32_16x16x32_f16(af[m], bf[g], acc[m][g], 0, 0, 0);
            }
        }
    }

    // ---- Epilogue: gate math; lane owns hid = 16*w4 + lane15 ----
    const int hid = w4 * 16 + lane15;
    const float bi = bias[hid], bff = bias[64 + hid];
    const float bo = bias[128 + hid], bg = bias[192 + hid];
    float osum = 0.f, osum2 = 0.f;
#pragma unroll
    for (int m = 0; m < 2; ++m) {
        int xb = (mh * 2 + m) * 16 + kq * 4;
        size_t pixbase = (size_t)(b * 64 + y0) * 64 + xb;
        float4 o4;
#pragma unroll
        for (int r = 0; r < 4; ++r) {
            float ci = acc[m][0][r] + bi;
            float cf = acc[m][1][r] + bff;
            float co = acc[m][2][r] + bo;
            float cg_ = acc[m][3][r] + bg;
            size_t ca = (pixbase + r) * 64 + hid;
            float c_old = (t > 0) ? c_ws[ca] : 0.f;
            float si = 1.f / (1.f + __expf(-ci));
            float sf = 1.f / (1.f + __expf(-cf));
            float so = 1.f / (1.f + __expf(-co));
            float c_new = sf * c_old + si * tanh_fast(cg_);
            float h = so * tanh_fast(c_new);
            if (t < TT - 1) {
                c_ws[ca] = c_new;
                h_out[ca] = (_Float16)h;
            }
            float ov = (h >= 0.f) ? h : NEG_SLOPE * h;
            (&o4.x)[r] = ov;
            osum += ov;
            osum2 += ov * ov;
        }
        *(float4*)(out + (((size_t)(b * TT + t) * 64 + hid) * 64 + y0) * 64 + xb) = o4;
    }
    osum  += __shfl_xor(osum, 16);  osum  += __shfl_xor(osum, 32);
    osum2 += __shfl_xor(osum2, 16); osum2 += __shfl_xor(osum2, 32);
    if (kq == 0) {
        int row2 = (b * 64 + y0) * 2 + mh;
        if (t == 0) {
            partial[row2 * 128 + hid] = osum;
            partial[row2 * 128 + 64 + hid] = osum2;
        } else {
            partial[row2 * 128 + hid] += osum;
            partial[row2 * 128 + 64 + hid] += osum2;
        }
    }
}

__global__ __launch_bounds__(512) void finalize_stats(const float* __restrict__ partial,
                                                      float* __restrict__ stats,
                                                      const float* __restrict__ gamma,
                                                      const float* __restrict__ beta) {
    int idx = threadIdx.x & 127;
    int seg = threadIdx.x >> 7;       // 0..3, each sums 256 of 1024 rows
    float s = 0.f;
    for (int k = seg * 256; k < seg * 256 + 256; ++k) s += partial[k * 128 + idx];
    __shared__ float red[4][128];
    red[seg][idx] = s;
    __syncthreads();
    if (threadIdx.x < 64) {
        int hid = threadIdx.x;
        const float n = (float)((size_t)BB * TT * HH * WW);
        float mean = (red[0][hid] + red[1][hid] + red[2][hid] + red[3][hid]) / n;
        float var  = (red[0][64 + hid] + red[1][64 + hid] + red[2][64 + hid] + red[3][64 + hid]) / n
                     - mean * mean;
        float inv  = rsqrtf(var + EPS);
        float sc   = gamma[hid] * inv;
        stats[hid]      = sc;
        stats[64 + hid] = beta[hid] - mean * sc;
    }
}

__global__ __launch_bounds__(256) void normalize_k(float* __restrict__ out,
                                                   const float* __restrict__ stats) {
    const size_t N = (size_t)BB * TT * HID * HH * WW;
    size_t i = ((size_t)blockIdx.x * blockDim.x + threadIdx.x) * 4;
    size_t stride = (size_t)gridDim.x * blockDim.x * 4;
    for (; i < N; i += stride) {
        int ch = (int)((i >> 12) & (HID - 1));
        float sc = stats[ch], sh = stats[64 + ch];
        float4 v = *(float4*)(out + i);
        v.x = fmaf(v.x, sc, sh);
        v.y = fmaf(v.y, sc, sh);
        v.z = fmaf(v.z, sc, sh);
        v.w = fmaf(v.w, sc, sh);
        *(float4*)(out + i) = v;
    }
}

extern "C" void kernel_launch(void* const* d_in, const int* in_sizes, int n_in,
                              void* d_out, int out_size, void* d_ws, size_t ws_size,
                              hipStream_t stream) {
    const float* x     = (const float*)d_in[0];
    const float* w     = (const float*)d_in[1];
    const float* bias  = (const float*)d_in[2];
    const float* gamma = (const float*)d_in[3];
    const float* beta  = (const float*)d_in[4];
    float* out = (float*)d_out;
    char* wsb = (char*)d_ws;

    // Total workspace: 51,298,816 B (r0/r1 proved 59.3 MB works; r3's 101 MB
    // is the suspected container killer — stay well under).
    _Float16* xcl   = (_Float16*)(wsb);                    // 33,554,432 B
    _Float16* wpk   = (_Float16*)(wsb + 33554432);         //    442,368 B
    _Float16* hA    = (_Float16*)(wsb + 33996800);         //  4,194,304 B
    _Float16* hB    = (_Float16*)(wsb + 38191104);         //  4,194,304 B
    float* c_ws     = (float*)(wsb + 42385408);            //  8,388,608 B
    float* partial  = (float*)(wsb + 50774016);            //    524,288 B
    float* stats    = (float*)(wsb + 51298304);            //        512 B

    x2h<<<dim3(64, 16, 8), 256, 0, stream>>>(x, xcl);
    pack_wh<<<864, 256, 0, stream>>>(w, wpk);

    _Float16* hin = hA;
    _Float16* hout = hB;
    for (int t = 0; t < TT; ++t) {
        lstm_step<<<dim3(64, 8), 512, 0, stream>>>(xcl, wpk, bias, hin, hout,
                                                   c_ws, out, partial, t);
        _Float16* tmp = hin; hin = hout; hout = tmp;
    }
    finalize_stats<<<1, 512, 0, stream>>>(partial, stats, gamma, beta);
    normalize_k<<<8192, 256, 0, stream>>>(out, stats);
}

// Round 7
// 650.823 us; speedup vs baseline: 1.7024x; 1.0004x over previous
//
#include <hip/hip_runtime.h>

#define BB 8
#define TT 16
#define CIN 32
#define HID 64
#define HH 64
#define WW 64
#define EPS 1e-3f
#define NEG_SLOPE 0.01f

typedef short s16x8 __attribute__((ext_vector_type(8)));
typedef _Float16 hx8 __attribute__((ext_vector_type(8)));
typedef float fx4 __attribute__((ext_vector_type(4)));

__device__ __forceinline__ float tanh_fast(float x) {
    x = fminf(fmaxf(x, -15.f), 15.f);
    float e = __expf(-2.f * x);
    return (1.f - e) / (1.f + e);
}

// x (NCHW fp32) -> xcl [b][t][y*64+x][32] f16
__global__ __launch_bounds__(256) void x2h(const float* __restrict__ x,
                                           _Float16* __restrict__ xcl) {
    __shared__ float s[32][65];
    int y = blockIdx.x, t = blockIdx.y, b = blockIdx.z;
    int tid = threadIdx.x;
    const float* src = x + (((size_t)(b * TT + t) * CIN) * HH + y) * WW;
#pragma unroll
    for (int k = 0; k < 8; ++k) {
        int idx = tid + k * 256;
        int c = idx >> 6, xx = idx & 63;
        s[c][xx] = src[(size_t)c * HH * WW + xx];
    }
    __syncthreads();
    int xx = tid >> 2, c0 = (tid & 3) * 8;
    _Float16 tmp[8];
#pragma unroll
    for (int j = 0; j < 8; ++j) tmp[j] = (_Float16)s[c0 + j][xx];
    _Float16* dst = xcl + (((size_t)(b * TT + t) * 4096) + y * 64 + xx) * 32 + c0;
    *(hx8*)dst = *(hx8*)tmp;
}

// w [256 oc][96 ch][3][3] fp32 -> wpk [tap(9)][kc(3)][kq(4)][n(256)][k7(8)] f16
// n-mapping: gate=(n>>4)&3, hid=(n>>6)*16+(n&15), oc=gate*64+hid
// channel ks = kc*32 + kq*8 + k7 of concat [x(32), h(64)]
__global__ __launch_bounds__(256) void pack_wh(const float* __restrict__ w,
                                               _Float16* __restrict__ wpk) {
    int idx = blockIdx.x * 256 + threadIdx.x;
    if (idx >= 256 * 864) return;
    int k7 = idx & 7;
    int j = idx >> 3;
    int n = j & 255;
    int kk = j >> 8;            // tap*12 + kc*4 + kq
    int tap = kk / 12;
    int r12 = kk % 12;
    int ks = (r12 >> 2) * 32 + (r12 & 3) * 8 + k7;
    int gate = (n >> 4) & 3;
    int hid  = (n >> 6) * 16 + (n & 15);
    int oc   = gate * 64 + hid;
    wpk[idx] = (_Float16)w[((size_t)oc * 96 + ks) * 9 + tap];
}

// One timestep. grid (64 rows, 8 b) x 512 thr = 8 waves, 2 blocks/CU (4/SIMD).
// UNIFIED tile: x (ch 0..31) and h (ch 32..95) staged into one LDS tile of
// 3 rows x 66 cols x 96ch f16 @ stride 104 shorts (bank-clean for b128).
// Single barrier; then ONE rolled tap loop (9 iters, kc x3 unrolled inside):
// per (tap,kc): 4 coalesced bf loads (L2) + 2 ds_read_b128 + 8 MFMAs.
// Rationale: r0/r1/r5 showed per-step time nearly occupancy-INSENSITIVE
// (1/2/4 waves per SIMD -> 47/45/37 us). Suspect: ~14 KB of straight-line
// unrolled code cold-marched from invalidated L2 every launch + duplicated
// X/H phase bodies. This version's hot loop is ~2 KB.
// [RESUBMIT of round-6 source: all LDS/global indices audited in-bounds;
//  workspace layout byte-identical to the r5 run that passed. The round-6
//  "container failed twice" is attributed to infra flake (r5 push took 974s).]
__global__ __launch_bounds__(512, 4) void lstm_step(
    const _Float16* __restrict__ xcl,
    const _Float16* __restrict__ wpk,
    const float* __restrict__ bias,
    const _Float16* __restrict__ h_in,
    _Float16* __restrict__ h_out,
    float* __restrict__ c_ws,
    float* __restrict__ out,
    float* __restrict__ partial,
    int t) {
    const int y0 = blockIdx.x, b = blockIdx.y;
    const int tid = threadIdx.x;
    const int lane15 = tid & 15;
    const int kq = (tid >> 4) & 3;
    const int w = tid >> 6;          // 0..7
    const int w4 = w & 3;            // N quadrant
    const int mh = w >> 2;           // M half

    __shared__ __align__(16) unsigned short s_t[3 * 66 * 104];   // 41,184 B

    // ---- stage x: 3 rows x 66 cols x 32ch (units 0..3) ----
    const short* xb_t = (const short*)xcl + (size_t)(b * TT + t) * 4096 * 32;
    for (int u = tid; u < 3 * 66 * 4; u += 512) {
        int unit = u & 3, pix = u >> 2;
        int col = pix % 66, r = pix / 66;
        int iy = y0 + r - 1, ix = col - 1;
        s16x8 v = (s16x8)0;
        if (iy >= 0 && iy < 64 && ix >= 0 && ix < 64)
            v = *(const s16x8*)(xb_t + ((size_t)iy * 64 + ix) * 32 + unit * 8);
        *(s16x8*)(s_t + (r * 66 + col) * 104 + unit * 8) = v;
    }
    // ---- stage h (t>0): 3 rows x 66 cols x 64ch (ch offset 32) ----
    if (t > 0) {
        for (int u = tid; u < 3 * 66 * 8; u += 512) {
            int unit = u & 7, pix = u >> 3;
            int col = pix % 66, r = pix / 66;
            int iy = y0 + r - 1, ix = col - 1;
            s16x8 v = (s16x8)0;
            if (iy >= 0 && iy < 64 && ix >= 0 && ix < 64)
                v = *(const s16x8*)((const short*)h_in +
                                    ((size_t)(b * 64 + iy) * 64 + ix) * 64 + unit * 8);
            *(s16x8*)(s_t + (r * 66 + col) * 104 + 32 + unit * 8) = v;
        }
    }
    __syncthreads();

    fx4 acc[2][4];
#pragma unroll
    for (int m = 0; m < 2; ++m)
#pragma unroll
        for (int g = 0; g < 4; ++g) acc[m][g] = (fx4)0.f;

    const int nbase = 4 * w4 * 16 + lane15;          // n for g=0
    const int colb0 = (mh * 2 + 0) * 16 + lane15;    // col for m=0 (kx=0)
    const int colb1 = (mh * 2 + 1) * 16 + lane15;

    if (t > 0) {
#pragma unroll 1
        for (int tap = 0; tap < 9; ++tap) {
            const int ky = tap / 3, kx = tap % 3;
            const unsigned short* a0 = s_t + (ky * 66 + colb0 + kx) * 104 + kq * 8;
            const unsigned short* a1 = s_t + (ky * 66 + colb1 + kx) * 104 + kq * 8;
            const _Float16* wp = wpk + ((size_t)(tap * 12 + kq) * 256 + nbase) * 8;
#pragma unroll
            for (int kc = 0; kc < 3; ++kc) {
                hx8 bf[4];
#pragma unroll
                for (int g = 0; g < 4; ++g)
                    bf[g] = *(const hx8*)(wp + (size_t)(kc * 4) * 256 * 8 + g * 16 * 8);
                hx8 af0 = *(const hx8*)(a0 + kc * 32);
                hx8 af1 = *(const hx8*)(a1 + kc * 32);
#pragma unroll
                for (int g = 0; g < 4; ++g) {
                    acc[0][g] = __builtin_amdgcn_mfma_f32_16x16x32_f16(af0, bf[g], acc[0][g], 0, 0, 0);
                    acc[1][g] = __builtin_amdgcn_mfma_f32_16x16x32_f16(af1, bf[g], acc[1][g], 0, 0, 0);
                }
            }
        }
    } else {
#pragma unroll 1
        for (int tap = 0; tap < 9; ++tap) {
            const int ky = tap / 3, kx = tap % 3;
            const unsigned short* a0 = s_t + (ky * 66 + colb0 + kx) * 104 + kq * 8;
            const unsigned short* a1 = s_t + (ky * 66 + colb1 + kx) * 104 + kq * 8;
            const _Float16* wp = wpk + ((size_t)(tap * 12 + kq) * 256 + nbase) * 8;
            hx8 bf[4];
#pragma unroll
            for (int g = 0; g < 4; ++g)
                bf[g] = *(const hx8*)(wp + g * 16 * 8);
            hx8 af0 = *(const hx8*)a0;
            hx8 af1 = *(const hx8*)a1;
#pragma unroll
            for (int g = 0; g < 4; ++g) {
                acc[0][g] = __builtin_amdgcn_mfma_f32_16x16x32_f16(af0, bf[g], acc[0][g], 0, 0, 0);
                acc[1][g] = __builtin_amdgcn_mfma_f32_16x16x32_f16(af1, bf[g], acc[1][g], 0, 0, 0);
            }
        }
    }

    // ---- Epilogue: gate math; lane owns hid = 16*w4 + lane15 ----
    const int hid = w4 * 16 + lane15;
    const float bi = bias[hid], bff = bias[64 + hid];
    const float bo = bias[128 + hid], bg = bias[192 + hid];
    float osum = 0.f, osum2 = 0.f;
#pragma unroll
    for (int m = 0; m < 2; ++m) {
        int xb = (mh * 2 + m) * 16 + kq * 4;
        size_t pixbase = (size_t)(b * 64 + y0) * 64 + xb;
        float4 o4;
#pragma unroll
        for (int r = 0; r < 4; ++r) {
            float ci = acc[m][0][r] + bi;
            float cf = acc[m][1][r] + bff;
            float co = acc[m][2][r] + bo;
            float cg_ = acc[m][3][r] + bg;
            size_t ca = (pixbase + r) * 64 + hid;
            float c_old = (t > 0) ? c_ws[ca] : 0.f;
            float si = 1.f / (1.f + __expf(-ci));
            float sf = 1.f / (1.f + __expf(-cf));
            float so = 1.f / (1.f + __expf(-co));
            float c_new = sf * c_old + si * tanh_fast(cg_);
            float h = so * tanh_fast(c_new);
            if (t < TT - 1) {
                c_ws[ca] = c_new;
                h_out[ca] = (_Float16)h;
            }
            float ov = (h >= 0.f) ? h : NEG_SLOPE * h;
            (&o4.x)[r] = ov;
            osum += ov;
            osum2 += ov * ov;
        }
        *(float4*)(out + (((size_t)(b * TT + t) * 64 + hid) * 64 + y0) * 64 + xb) = o4;
    }
    osum  += __shfl_xor(osum, 16);  osum  += __shfl_xor(osum, 32);
    osum2 += __shfl_xor(osum2, 16); osum2 += __shfl_xor(osum2, 32);
    if (kq == 0) {
        int row2 = (b * 64 + y0) * 2 + mh;
        if (t == 0) {
            partial[row2 * 128 + hid] = osum;
            partial[row2 * 128 + 64 + hid] = osum2;
        } else {
            partial[row2 * 128 + hid] += osum;
            partial[row2 * 128 + 64 + hid] += osum2;
        }
    }
}

__global__ __launch_bounds__(512) void finalize_stats(const float* __restrict__ partial,
                                                      float* __restrict__ stats,
                                                      const float* __restrict__ gamma,
                                                      const float* __restrict__ beta) {
    int idx = threadIdx.x & 127;
    int seg = threadIdx.x >> 7;       // 0..3, each sums 256 of 1024 rows
    float s = 0.f;
    for (int k = seg * 256; k < seg * 256 + 256; ++k) s += partial[k * 128 + idx];
    __shared__ float red[4][128];
    red[seg][idx] = s;
    __syncthreads();
    if (threadIdx.x < 64) {
        int hid = threadIdx.x;
        const float n = (float)((size_t)BB * TT * HH * WW);
        float mean = (red[0][hid] + red[1][hid] + red[2][hid] + red[3][hid]) / n;
        float var  = (red[0][64 + hid] + red[1][64 + hid] + red[2][64 + hid] + red[3][64 + hid]) / n
                     - mean * mean;
        float inv  = rsqrtf(var + EPS);
        float sc   = gamma[hid] * inv;
        stats[hid]      = sc;
        stats[64 + hid] = beta[hid] - mean * sc;
    }
}

__global__ __launch_bounds__(256) void normalize_k(float* __restrict__ out,
                                                   const float* __restrict__ stats) {
    const size_t N = (size_t)BB * TT * HID * HH * WW;
    size_t i = ((size_t)blockIdx.x * blockDim.x + threadIdx.x) * 4;
    size_t stride = (size_t)gridDim.x * blockDim.x * 4;
    for (; i < N; i += stride) {
        int ch = (int)((i >> 12) & (HID - 1));
        float sc = stats[ch], sh = stats[64 + ch];
        float4 v = *(float4*)(out + i);
        v.x = fmaf(v.x, sc, sh);
        v.y = fmaf(v.y, sc, sh);
        v.z = fmaf(v.z, sc, sh);
        v.w = fmaf(v.w, sc, sh);
        *(float4*)(out + i) = v;
    }
}

extern "C" void kernel_launch(void* const* d_in, const int* in_sizes, int n_in,
                              void* d_out, int out_size, void* d_ws, size_t ws_size,
                              hipStream_t stream) {
    const float* x     = (const float*)d_in[0];
    const float* w     = (const float*)d_in[1];
    const float* bias  = (const float*)d_in[2];
    const float* gamma = (const float*)d_in[3];
    const float* beta  = (const float*)d_in[4];
    float* out = (float*)d_out;
    char* wsb = (char*)d_ws;

    // Total workspace: 51,298,816 B (r5-proven layout).
    _Float16* xcl   = (_Float16*)(wsb);                    // 33,554,432 B
    _Float16* wpk   = (_Float16*)(wsb + 33554432);         //    442,368 B
    _Float16* hA    = (_Float16*)(wsb + 33996800);         //  4,194,304 B
    _Float16* hB    = (_Float16*)(wsb + 38191104);         //  4,194,304 B
    float* c_ws     = (float*)(wsb + 42385408);            //  8,388,608 B
    float* partial  = (float*)(wsb + 50774016);            //    524,288 B
    float* stats    = (float*)(wsb + 51298304);            //        512 B

    x2h<<<dim3(64, 16, 8), 256, 0, stream>>>(x, xcl);
    pack_wh<<<864, 256, 0, stream>>>(w, wpk);

    _Float16* hin = hA;
    _Float16* hout = hB;
    for (int t = 0; t < TT; ++t) {
        lstm_step<<<dim3(64, 8), 512, 0, stream>>>(xcl, wpk, bias, hin, hout,
                                                   c_ws, out, partial, t);
        _Float16* tmp = hin; hin = hout; hout = tmp;
    }
    finalize_stats<<<1, 512, 0, stream>>>(partial, stats, gamma, beta);
    normalize_k<<<8192, 256, 0, stream>>>(out, stats);
}